// Round 16
// baseline (553.054 us; speedup 1.0000x reference)
//
#include <hip/hip_runtime.h>

typedef unsigned short u16;
typedef __attribute__((ext_vector_type(8))) short bh8;   // 8 bf16 in 4 VGPRs
typedef __attribute__((ext_vector_type(4))) short sh4;   // 4 bf16 = 8B
typedef __attribute__((ext_vector_type(4))) float fx4;

constexpr int B = 16, S = 512, D = 512, H = 8, DFF = 2048, NL = 4, DK = 64;
constexpr int M = B * S;  // 8192

__device__ __forceinline__ u16 f2bf(float f) {
  union { float f; unsigned u; } v; v.f = f;
  unsigned r = v.u + 0x7fffu + ((v.u >> 16) & 1u);
  return (u16)(r >> 16);
}
__device__ __forceinline__ float bf2f(u16 b) {
  union { unsigned u; float f; } v; v.u = ((unsigned)b) << 16;
  return v.f;
}

__device__ __forceinline__ void gload16(const void* g, void* l) {
  __builtin_amdgcn_global_load_lds((const __attribute__((address_space(1))) void*)g,
                                   (__attribute__((address_space(3))) void*)l,
                                   16, 0, 0);
}

// ---------------- xb = bf16(q + pe), yb = bf16(qa + pe) ----------------
__global__ __launch_bounds__(256) void add_pe(
    const float* __restrict__ q, const float* __restrict__ qa,
    const float* __restrict__ pe,
    u16* __restrict__ xb, u16* __restrict__ yb) {
  int idx = blockIdx.x * 256 + threadIdx.x;
  float pv = pe[idx & (S * D - 1)];
  xb[idx] = f2bf(q[idx] + pv);
  yb[idx] = f2bf(qa[idx] + pv);
}

// ---------------- weight transpose+convert: src f32 [K][N] -> dst bf16 [N][K] ----------------
__device__ __forceinline__ void transpose_tile(
    const float* __restrict__ s, u16* __restrict__ d, int K, int N,
    int k0, int n0) {
  __shared__ float t[64][65];
  const int tid = threadIdx.x;
  const int r = tid >> 2, c0 = (tid & 3) * 16;
#pragma unroll
  for (int i = 0; i < 16; i += 4) {
    float4 v = *(const float4*)&s[(size_t)(k0 + r) * N + n0 + c0 + i];
    t[r][c0 + i] = v.x; t[r][c0 + i + 1] = v.y;
    t[r][c0 + i + 2] = v.z; t[r][c0 + i + 3] = v.w;
  }
  __syncthreads();
  u16 tmp[16];
#pragma unroll
  for (int i = 0; i < 16; i++) tmp[i] = f2bf(t[c0 + i][r]);
  *(fx4*)&d[(size_t)(n0 + r) * K + k0 + c0] = *(fx4*)&tmp[0];
  *(fx4*)&d[(size_t)(n0 + r) * K + k0 + c0 + 8] = *(fx4*)&tmp[8];
}

__global__ __launch_bounds__(256) void transpose_cvt(
    const float* __restrict__ src, u16* __restrict__ dst, int K, int N) {
  const int l = blockIdx.z;
  transpose_tile(src + (size_t)l * K * N, dst + (size_t)l * N * K, K, N,
                 blockIdx.y * 64, blockIdx.x * 64);
}

__global__ __launch_bounds__(256) void transpose_cvt3(
    const float* __restrict__ Wk, const float* __restrict__ Wv,
    const float* __restrict__ Wo, u16* __restrict__ Wkt,
    u16* __restrict__ Wvt, u16* __restrict__ Wot) {
  const int z = blockIdx.z;
  const int which = z >> 2, l = z & 3;
  const float* s = (which == 0 ? Wk : which == 1 ? Wv : Wo) + (size_t)l * D * D;
  u16* d = (which == 0 ? Wkt : which == 1 ? Wvt : Wot) + (size_t)l * D * D;
  transpose_tile(s, d, D, D, blockIdx.y * 64, blockIdx.x * 64);
}

// ---------------- bf16 MFMA GEMM tile core: 2-phase double-buffered, BK in {32,64} ----------------
template <int NT, int BM, int BN, int BK, int RELU, int OUTBF>
__device__ __forceinline__ void gemm_tile_core(
    const u16* __restrict__ A, const u16* __restrict__ Wt,
    const float* __restrict__ bias, void* __restrict__ Cout,
    int N, int K, int arow, int bcol, u16* Al, u16* Bl) {
  constexpr int NW = NT / 64;
  constexpr int WC = NW / 2;
  constexpr int MR = BM / 32;
  constexpr int NR = BN / (WC * 16);
  constexpr int GPB = BK / 8;            // 16B groups per LDS row
  constexpr int GM = GPB - 1;
  constexpr int KS = BK / 32;            // mfma K-steps per tile
  constexpr int ACH = (BM * BK) / (8 * NT), BCH = (BN * BK) / (8 * NT);
  constexpr int ABUF = BM * BK, BBUF = BN * BK;

  const int tid = threadIdx.x;
  const int lane = tid & 63, w = tid >> 6;
  const int li = lane & 15, lg = lane >> 4;
  const int wrow = (w / WC) * (BM / 2), wcol = (w % WC) * (BN / WC);

  const fx4 zero = {0.f, 0.f, 0.f, 0.f};
  fx4 acc[MR][NR];
#pragma unroll
  for (int i = 0; i < MR; i++)
#pragma unroll
    for (int j = 0; j < NR; j++) acc[i][j] = zero;

  auto stage = [&](int buf, int k0) {
#pragma unroll
    for (int i = 0; i < ACH; i++) {
      int c = i * NT + tid, r = c / GPB, g = c & GM;
      gload16(&A[(size_t)(arow + r) * K + k0 + ((g ^ (r & GM)) << 3)],
              &Al[buf * ABUF + (i * NW + w) * 512]);
    }
#pragma unroll
    for (int i = 0; i < BCH; i++) {
      int c = i * NT + tid, r = c / GPB, g = c & GM;
      gload16(&Wt[(size_t)(bcol + r) * K + k0 + ((g ^ (r & GM)) << 3)],
              &Bl[buf * BBUF + (i * NW + w) * 512]);
    }
  };
  auto compute = [&](int buf) {
#pragma unroll
    for (int ks = 0; ks < KS; ks++) {
      bh8 am[MR], bn[NR];
#pragma unroll
      for (int mi = 0; mi < MR; mi++) {
        int r = wrow + mi * 16 + li;
        am[mi] = *(const bh8*)&Al[buf * ABUF + r * BK + (((ks * 4 + lg) ^ (r & GM)) << 3)];
      }
#pragma unroll
      for (int ni = 0; ni < NR; ni++) {
        int r = wcol + ni * 16 + li;
        bn[ni] = *(const bh8*)&Bl[buf * BBUF + r * BK + (((ks * 4 + lg) ^ (r & GM)) << 3)];
      }
#pragma unroll
      for (int mi = 0; mi < MR; mi++)
#pragma unroll
        for (int ni = 0; ni < NR; ni++)
          acc[mi][ni] = __builtin_amdgcn_mfma_f32_16x16x32_bf16(am[mi], bn[ni], acc[mi][ni], 0, 0, 0);
    }
  };

  stage(0, 0);
  __syncthreads();
  const int nk = K / BK;
  int cur = 0;
  for (int t = 0; t < nk - 1; t++) {
    stage(cur ^ 1, (t + 1) * BK);
    compute(cur);
    __syncthreads();
    cur ^= 1;
  }
  compute(cur);

  float bv[NR];
#pragma unroll
  for (int ni = 0; ni < NR; ni++) bv[ni] = bias[bcol + wcol + ni * 16 + li];
#pragma unroll
  for (int mi = 0; mi < MR; mi++)
#pragma unroll
    for (int rr = 0; rr < 4; rr++) {
      int row = arow + wrow + mi * 16 + lg * 4 + rr;
#pragma unroll
      for (int ni = 0; ni < NR; ni++) {
        int col = bcol + wcol + ni * 16 + li;
        float v = acc[mi][ni][rr] + bv[ni];
        if (RELU) v = fmaxf(v, 0.f);
        if (OUTBF) ((u16*)Cout)[(size_t)row * N + col] = f2bf(v);
        else ((float*)Cout)[(size_t)row * N + col] = v;
      }
    }
}

template <int NT, int BM, int BN, int BK, int RELU, int OUTBF>
__global__ __launch_bounds__(NT) void gemm2(
    const u16* __restrict__ A, const u16* __restrict__ Wt,
    const float* __restrict__ bias, void* __restrict__ Cout, int N, int K, int ntn) {
  __shared__ u16 Al[2 * BM * BK];
  __shared__ u16 Bl[2 * BN * BK];
  const int cpx = gridDim.x >> 3;
  const int swz = (blockIdx.x & 7) * cpx + (blockIdx.x >> 3);
  gemm_tile_core<NT, BM, BN, BK, RELU, OUTBF>(A, Wt, bias, Cout, N, K,
                                              (swz / ntn) * BM, (swz % ntn) * BN, Al, Bl);
}

// fused QK + V projections (independent GEMMs selected by blockIdx.y), 128x128 BK=64
__global__ __launch_bounds__(256) void gemm2_dual(
    const u16* __restrict__ A0, const u16* __restrict__ W0,
    const float* __restrict__ b0, u16* __restrict__ C0,
    const u16* __restrict__ A1, const u16* __restrict__ W1,
    const float* __restrict__ b1, u16* __restrict__ C1, int N, int K, int ntn) {
  __shared__ u16 Al[2 * 128 * 64];
  __shared__ u16 Bl[2 * 128 * 64];
  const u16* A = blockIdx.y ? A1 : A0;
  const u16* Wt = blockIdx.y ? W1 : W0;
  const float* bias = blockIdx.y ? b1 : b0;
  u16* C = blockIdx.y ? C1 : C0;
  const int cpx = gridDim.x >> 3;
  const int swz = (blockIdx.x & 7) * cpx + (blockIdx.x >> 3);
  gemm_tile_core<256, 128, 128, 64, 0, 1>(A, Wt, bias, C, N, K,
                                          (swz / ntn) * 128, (swz % ntn) * 128, Al, Bl);
}

// ---------------- flash attention: scores = (qk qk^T)*scale*fr, strict causal ----------------
// 256 q-rows per block as TWO strips (r and r+256) sharing one K/V staging.
__global__ __launch_bounds__(512) void attn_mfma(
    const u16* __restrict__ qk, const u16* __restrict__ vv,
    const float* __restrict__ fr, u16* __restrict__ att) {
  __shared__ u16 Kl[64 * 64];
  __shared__ u16 Vt[64 * 72];
  __shared__ u16 Pl[8][16 * 72];
  const int tid = threadIdx.x;
  const int lane = tid & 63, w = tid >> 6;
  const int li = lane & 15, lg = lane >> 4;
  const int bh = blockIdx.x & 127;
  const int q0 = (blockIdx.x >> 7) * 128;   // 0 or 128
  const int b = bh >> 3, h = bh & 7;

  const size_t rowbase = (size_t)(b * S) * D + h * DK;

  bh8 aq[2][2];
  float frs[2][4];
  fx4 o_[2][4];
  float m_[2][4], l_[2][4];
  const fx4 zero = {0.f, 0.f, 0.f, 0.f};
#pragma unroll
  for (int s = 0; s < 2; s++) {
    const int rs0 = q0 + s * 256 + w * 16;
#pragma unroll
    for (int ks = 0; ks < 2; ks++)
      aq[s][ks] = *(const bh8*)&qk[rowbase + (size_t)(rs0 + li) * D + ks * 32 + lg * 8];
#pragma unroll
    for (int rr = 0; rr < 4; rr++)
      frs[s][rr] = 0.125f * fr[b * S + rs0 + lg * 4 + rr];
#pragma unroll
    for (int i = 0; i < 4; i++) { o_[s][i] = zero; m_[s][i] = -1e30f; l_[s][i] = 0.f; }
  }

  const int ktmax = (q0 + 383) >> 6;   // q0=0 -> 5, q0=128 -> 7
  const int vj = tid & 63, vd0 = (tid >> 6) * 8;

  for (int kt = 0; kt <= ktmax; kt++) {
    {
      int r = tid >> 3, g = tid & 7;
      fx4 kvv = *(const fx4*)&qk[rowbase + (size_t)(kt * 64 + r) * D + ((g ^ (r & 7)) * 8)];
      *(fx4*)&Kl[r * 64 + g * 8] = kvv;
    }
    {
      u16 tmp[8];
      *(fx4*)&tmp[0] = *(const fx4*)&vv[rowbase + (size_t)(kt * 64 + vj) * D + vd0];
#pragma unroll
      for (int qd = 0; qd < 8; qd++) Vt[(vd0 + qd) * 72 + vj] = tmp[qd];
    }
    __syncthreads();

#pragma unroll
    for (int s = 0; s < 2; s++) {
      const int rs0 = q0 + s * 256 + w * 16;
      if (kt * 64 <= rs0 + 15) {
        fx4 sc[4];
#pragma unroll
        for (int jt = 0; jt < 4; jt++) sc[jt] = zero;
        __builtin_amdgcn_s_setprio(1);
#pragma unroll
        for (int ks = 0; ks < 2; ks++) {
          bh8 bk[4];
#pragma unroll
          for (int jt = 0; jt < 4; jt++) {
            int r = jt * 16 + li;
            bk[jt] = *(const bh8*)&Kl[r * 64 + (((ks * 4 + lg) ^ (r & 7)) * 8)];
          }
#pragma unroll
          for (int jt = 0; jt < 4; jt++)
            sc[jt] = __builtin_amdgcn_mfma_f32_16x16x32_bf16(aq[s][ks], bk[jt], sc[jt], 0, 0, 0);
        }
        __builtin_amdgcn_s_setprio(0);

        const bool diag = (kt == (rs0 >> 6));
        const int rbase = rs0 & 63;
#pragma unroll
        for (int jt = 0; jt < 4; jt++)
#pragma unroll
          for (int rr = 0; rr < 4; rr++) {
            float sv = sc[jt][rr] * frs[s][rr];
            if (diag && (jt * 16 + li >= rbase + lg * 4 + rr)) sv = -1e30f;
            sc[jt][rr] = sv;
          }

#pragma unroll
        for (int rr = 0; rr < 4; rr++) {
          float v0 = fmaxf(fmaxf(sc[0][rr], sc[1][rr]), fmaxf(sc[2][rr], sc[3][rr]));
          v0 = fmaxf(v0, __shfl_xor(v0, 1));
          v0 = fmaxf(v0, __shfl_xor(v0, 2));
          v0 = fmaxf(v0, __shfl_xor(v0, 4));
          v0 = fmaxf(v0, __shfl_xor(v0, 8));
          float mn = fmaxf(m_[s][rr], v0);
          float cf = __expf(m_[s][rr] - mn);
          m_[s][rr] = mn;
          float ps = 0.f;
#pragma unroll
          for (int jt = 0; jt < 4; jt++) {
            float e = __expf(sc[jt][rr] - mn);
            sc[jt][rr] = e;
            ps += e;
          }
          ps += __shfl_xor(ps, 1);
          ps += __shfl_xor(ps, 2);
          ps += __shfl_xor(ps, 4);
          ps += __shfl_xor(ps, 8);
          l_[s][rr] = l_[s][rr] * cf + ps;
#pragma unroll
          for (int dt = 0; dt < 4; dt++) o_[s][dt][rr] *= cf;
        }

#pragma unroll
        for (int jt = 0; jt < 4; jt++)
#pragma unroll
          for (int rr = 0; rr < 4; rr++)
            Pl[w][(lg * 4 + rr) * 72 + jt * 16 + li] = f2bf(sc[jt][rr]);

        __builtin_amdgcn_s_setprio(1);
#pragma unroll
        for (int ks = 0; ks < 2; ks++) {
          bh8 pa = *(const bh8*)&Pl[w][li * 72 + ks * 32 + lg * 8];
          bh8 bvf[4];
#pragma unroll
          for (int dt = 0; dt < 4; dt++)
            bvf[dt] = *(const bh8*)&Vt[(dt * 16 + li) * 72 + ks * 32 + lg * 8];
#pragma unroll
          for (int dt = 0; dt < 4; dt++)
            o_[s][dt] = __builtin_amdgcn_mfma_f32_16x16x32_bf16(pa, bvf[dt], o_[s][dt], 0, 0, 0);
        }
        __builtin_amdgcn_s_setprio(0);
      }
    }
    __syncthreads();
  }

#pragma unroll
  for (int s = 0; s < 2; s++) {
#pragma unroll
    for (int rr = 0; rr < 4; rr++) {
      int rs = q0 + s * 256 + w * 16 + lg * 4 + rr;
      float inv = (rs == 0) ? 0.f : 1.f / l_[s][rr];
#pragma unroll
      for (int dt = 0; dt < 4; dt++)
        att[rowbase + (size_t)rs * D + dt * 16 + li] = f2bf(o_[s][dt][rr] * inv);
    }
  }
}

// ---------------- residual + LayerNorm: bf16 residual in, bf16 (and optional f32) out ----------------
__global__ __launch_bounds__(256) void add_ln(
    const u16* __restrict__ xinb, const u16* __restrict__ pb,
    const float* __restrict__ g, const float* __restrict__ bta,
    float* __restrict__ xoutf, u16* __restrict__ xb) {
  const int w = threadIdx.x >> 6, lane = threadIdx.x & 63;
  const int row = blockIdx.x * 4 + w;
  const u16* xi = &xinb[(size_t)row * D];
  const u16* pp = &pb[(size_t)row * D];

  sh4 x0 = *(const sh4*)&xi[lane * 4];
  sh4 x1 = *(const sh4*)&xi[256 + lane * 4];
  sh4 p0 = *(const sh4*)&pp[lane * 4];
  sh4 p1 = *(const sh4*)&pp[256 + lane * 4];
  float v[8] = {bf2f((u16)x0.x) + bf2f((u16)p0.x), bf2f((u16)x0.y) + bf2f((u16)p0.y),
                bf2f((u16)x0.z) + bf2f((u16)p0.z), bf2f((u16)x0.w) + bf2f((u16)p0.w),
                bf2f((u16)x1.x) + bf2f((u16)p1.x), bf2f((u16)x1.y) + bf2f((u16)p1.y),
                bf2f((u16)x1.z) + bf2f((u16)p1.z), bf2f((u16)x1.w) + bf2f((u16)p1.w)};

  float s = 0.f;
#pragma unroll
  for (int i = 0; i < 8; i++) s += v[i];
#pragma unroll
  for (int d = 1; d < 64; d <<= 1) s += __shfl_xor(s, d);
  const float mu = s * (1.0f / D);

  float vs = 0.f;
#pragma unroll
  for (int i = 0; i < 8; i++) { v[i] -= mu; vs += v[i] * v[i]; }
#pragma unroll
  for (int d = 1; d < 64; d <<= 1) vs += __shfl_xor(vs, d);
  const float rs = rsqrtf(vs * (1.0f / D) + 1e-5f);

  float4 g0 = *(const float4*)&g[lane * 4];
  float4 b0 = *(const float4*)&bta[lane * 4];
  float4 g1 = *(const float4*)&g[256 + lane * 4];
  float4 b1 = *(const float4*)&bta[256 + lane * 4];
  float o[8];
  o[0] = v[0] * rs * g0.x + b0.x; o[1] = v[1] * rs * g0.y + b0.y;
  o[2] = v[2] * rs * g0.z + b0.z; o[3] = v[3] * rs * g0.w + b0.w;
  o[4] = v[4] * rs * g1.x + b1.x; o[5] = v[5] * rs * g1.y + b1.y;
  o[6] = v[6] * rs * g1.z + b1.z; o[7] = v[7] * rs * g1.w + b1.w;

  if (xoutf) {
    *(float4*)&xoutf[(size_t)row * D + lane * 4] = *(float4*)&o[0];
    *(float4*)&xoutf[(size_t)row * D + 256 + lane * 4] = *(float4*)&o[4];
  }
  if (xb) {
    u16 ob[8];
#pragma unroll
    for (int i = 0; i < 8; i++) ob[i] = f2bf(o[i]);
    *(sh4*)&xb[(size_t)row * D + lane * 4] = *(sh4*)&ob[0];
    *(sh4*)&xb[(size_t)row * D + 256 + lane * 4] = *(sh4*)&ob[4];
  }
}

extern "C" void kernel_launch(void* const* d_in, const int* in_sizes, int n_in,
                              void* d_out, int out_size, void* d_ws, size_t ws_size,
                              hipStream_t stream) {
  const float* q_embed = (const float*)d_in[0];
  const float* qa_embed = (const float*)d_in[1];
  const float* forget_rate = (const float*)d_in[2];
  const float* pe = (const float*)d_in[3];
  const float* Wk = (const float*)d_in[4];
  const float* bk = (const float*)d_in[5];
  const float* Wv = (const float*)d_in[6];
  const float* bv = (const float*)d_in[7];
  const float* Wo = (const float*)d_in[8];
  const float* bo = (const float*)d_in[9];
  const float* ln1_g = (const float*)d_in[10];
  const float* ln1_b = (const float*)d_in[11];
  const float* W1 = (const float*)d_in[12];
  const float* b1 = (const float*)d_in[13];
  const float* W2 = (const float*)d_in[14];
  const float* b2 = (const float*)d_in[15];
  const float* ln2_g = (const float*)d_in[16];
  const float* ln2_b = (const float*)d_in[17];

  const size_t nMD = (size_t)M * D;
  char* p = (char*)d_ws;
  u16* projb = (u16*)p;      p += nMD * 2;
  u16* xb = (u16*)p;         p += nMD * 2;
  u16* yb = (u16*)p;         p += nMD * 2;
  u16* qkb = (u16*)p;        p += nMD * 2;
  u16* vvb = (u16*)p;        p += nMD * 2;
  u16* attb = (u16*)p;       p += nMD * 2;
  u16* hb = (u16*)p;         p += (size_t)M * DFF * 2;
  u16* Wkt = (u16*)p;        p += (size_t)NL * D * D * 2;
  u16* Wvt = (u16*)p;        p += (size_t)NL * D * D * 2;
  u16* Wot = (u16*)p;        p += (size_t)NL * D * D * 2;
  u16* W1t = (u16*)p;        p += (size_t)NL * D * DFF * 2;
  u16* W2t = (u16*)p;        p += (size_t)NL * DFF * D * 2;

  add_pe<<<(B * S * D) / 256, 256, 0, stream>>>(q_embed, qa_embed, pe, xb, yb);
  transpose_cvt3<<<dim3(D / 64, D / 64, 3 * NL), 256, 0, stream>>>(Wk, Wv, Wo, Wkt, Wvt, Wot);
  transpose_cvt<<<dim3(DFF / 64, D / 64, NL), 256, 0, stream>>>(W1, W1t, D, DFF);
  transpose_cvt<<<dim3(D / 64, DFF / 64, NL), 256, 0, stream>>>(W2, W2t, DFF, D);

  const int gD = (M / 64) * (D / 128);       // 512
  const int gD128 = (M / 128) * (D / 128);   // 256 (x2 via blockIdx.y in dual)
  const int gF128 = (M / 128) * (DFF / 128); // 1024

  for (int l = 0; l < NL; l++) {
    gemm2_dual<<<dim3(gD128, 2), 256, 0, stream>>>(
        xb, Wkt + (size_t)l * D * D, bk + l * D, qkb,
        yb, Wvt + (size_t)l * D * D, bv + l * D, vvb, D, D, D / 128);
    attn_mfma<<<256, 512, 0, stream>>>(qkb, vvb, forget_rate, attb);
    gemm2<256, 64, 128, 32, 0, 1><<<gD, 256, 0, stream>>>(
        attb, Wot + (size_t)l * D * D, bo + l * D, projb, D, D, D / 128);
    add_ln<<<M / 4, 256, 0, stream>>>(xb, projb, ln1_g + l * D, ln1_b + l * D,
                                      (float*)nullptr, xb);
    gemm2<256, 128, 128, 32, 1, 1><<<gF128, 256, 0, stream>>>(
        xb, W1t + (size_t)l * D * DFF, b1 + l * DFF, hb, DFF, D, DFF / 128);
    gemm2<256, 64, 128, 32, 0, 1><<<gD, 256, 0, stream>>>(
        hb, W2t + (size_t)l * DFF * D, b2 + l * D, projb, D, DFF, D / 128);
    float* xo = (l == NL - 1) ? (float*)d_out : (float*)nullptr;
    u16* xbo = (l == NL - 1) ? (u16*)nullptr : xb;
    add_ln<<<M / 4, 256, 0, stream>>>(xb, projb, ln2_g + l * D, ln2_b + l * D, xo, xbo);
  }
}

// Round 17
// 541.600 us; speedup vs baseline: 1.0211x; 1.0211x over previous
//
#include <hip/hip_runtime.h>

typedef unsigned short u16;
typedef __attribute__((ext_vector_type(8))) short bh8;   // 8 bf16 in 4 VGPRs
typedef __attribute__((ext_vector_type(4))) short sh4;   // 4 bf16 = 8B
typedef __attribute__((ext_vector_type(4))) float fx4;

constexpr int B = 16, S = 512, D = 512, H = 8, DFF = 2048, NL = 4, DK = 64;
constexpr int M = B * S;  // 8192

__device__ __forceinline__ u16 f2bf(float f) {
  union { float f; unsigned u; } v; v.f = f;
  unsigned r = v.u + 0x7fffu + ((v.u >> 16) & 1u);
  return (u16)(r >> 16);
}
__device__ __forceinline__ float bf2f(u16 b) {
  union { unsigned u; float f; } v; v.u = ((unsigned)b) << 16;
  return v.f;
}

__device__ __forceinline__ void gload16(const void* g, void* l) {
  __builtin_amdgcn_global_load_lds((const __attribute__((address_space(1))) void*)g,
                                   (__attribute__((address_space(3))) void*)l,
                                   16, 0, 0);
}

// ---------------- xb = bf16(q + pe), yb = bf16(qa + pe) ----------------
__global__ __launch_bounds__(256) void add_pe(
    const float* __restrict__ q, const float* __restrict__ qa,
    const float* __restrict__ pe,
    u16* __restrict__ xb, u16* __restrict__ yb) {
  int idx = blockIdx.x * 256 + threadIdx.x;
  float pv = pe[idx & (S * D - 1)];
  xb[idx] = f2bf(q[idx] + pv);
  yb[idx] = f2bf(qa[idx] + pv);
}

// ---------------- weight transpose+convert: src f32 [K][N] -> dst bf16 [N][K] ----------------
__device__ __forceinline__ void transpose_tile(
    const float* __restrict__ s, u16* __restrict__ d, int K, int N,
    int k0, int n0) {
  __shared__ float t[64][65];
  const int tid = threadIdx.x;
  const int r = tid >> 2, c0 = (tid & 3) * 16;
#pragma unroll
  for (int i = 0; i < 16; i += 4) {
    float4 v = *(const float4*)&s[(size_t)(k0 + r) * N + n0 + c0 + i];
    t[r][c0 + i] = v.x; t[r][c0 + i + 1] = v.y;
    t[r][c0 + i + 2] = v.z; t[r][c0 + i + 3] = v.w;
  }
  __syncthreads();
  u16 tmp[16];
#pragma unroll
  for (int i = 0; i < 16; i++) tmp[i] = f2bf(t[c0 + i][r]);
  *(fx4*)&d[(size_t)(n0 + r) * K + k0 + c0] = *(fx4*)&tmp[0];
  *(fx4*)&d[(size_t)(n0 + r) * K + k0 + c0 + 8] = *(fx4*)&tmp[8];
}

__global__ __launch_bounds__(256) void transpose_cvt(
    const float* __restrict__ src, u16* __restrict__ dst, int K, int N) {
  const int l = blockIdx.z;
  transpose_tile(src + (size_t)l * K * N, dst + (size_t)l * N * K, K, N,
                 blockIdx.y * 64, blockIdx.x * 64);
}

__global__ __launch_bounds__(256) void transpose_cvt3(
    const float* __restrict__ Wk, const float* __restrict__ Wv,
    const float* __restrict__ Wo, u16* __restrict__ Wkt,
    u16* __restrict__ Wvt, u16* __restrict__ Wot) {
  const int z = blockIdx.z;
  const int which = z >> 2, l = z & 3;
  const float* s = (which == 0 ? Wk : which == 1 ? Wv : Wo) + (size_t)l * D * D;
  u16* d = (which == 0 ? Wkt : which == 1 ? Wvt : Wot) + (size_t)l * D * D;
  transpose_tile(s, d, D, D, blockIdx.y * 64, blockIdx.x * 64);
}

// ---------------- bf16 MFMA GEMM tile core: 2-phase double-buffered ----------------
// BK=64: [r][128B] rows, XOR-8 swizzle. BK=32: paired rows (2r',2r'+1) share one
// 128B LDS row: addr = r'*128 + (r&1)*64 + ((g ^ (r'&3))*16) -> 2-way (free) banks.
template <int NT, int BM, int BN, int BK, int RELU, int OUTBF>
__device__ __forceinline__ void gemm_tile_core(
    const u16* __restrict__ A, const u16* __restrict__ Wt,
    const float* __restrict__ bias, void* __restrict__ Cout,
    int N, int K, int arow, int bcol, u16* Al, u16* Bl) {
  constexpr int NW = NT / 64;
  constexpr int WC = NW / 2;
  constexpr int MR = BM / 32;
  constexpr int NR = BN / (WC * 16);
  constexpr int KS = BK / 32;
  constexpr int ACH = (BM * BK) / (8 * NT), BCH = (BN * BK) / (8 * NT);
  constexpr int ABUF = BM * BK, BBUF = BN * BK;

  const int tid = threadIdx.x;
  const int lane = tid & 63, w = tid >> 6;
  const int li = lane & 15, lg = lane >> 4;
  const int wrow = (w / WC) * (BM / 2), wcol = (w % WC) * (BN / WC);

  const fx4 zero = {0.f, 0.f, 0.f, 0.f};
  fx4 acc[MR][NR];
#pragma unroll
  for (int i = 0; i < MR; i++)
#pragma unroll
    for (int j = 0; j < NR; j++) acc[i][j] = zero;

  // chunk c -> (row r, k-group g) for the staging source
  auto srcRG = [](int c, int& r, int& g) {
    if constexpr (BK == 64) {
      r = c >> 3;
      g = (c & 7) ^ (r & 7);
    } else {
      int rp = c >> 3, half = (c >> 2) & 1, gs = c & 3;
      r = rp * 2 + half;
      g = gs ^ (rp & 3);
    }
  };
  auto stage = [&](int buf, int k0) {
#pragma unroll
    for (int i = 0; i < ACH; i++) {
      int c = i * NT + tid, r, g;
      srcRG(c, r, g);
      gload16(&A[(size_t)(arow + r) * K + k0 + (g << 3)],
              &Al[buf * ABUF + (i * NW + w) * 512]);
    }
#pragma unroll
    for (int i = 0; i < BCH; i++) {
      int c = i * NT + tid, r, g;
      srcRG(c, r, g);
      gload16(&Wt[(size_t)(bcol + r) * K + k0 + (g << 3)],
              &Bl[buf * BBUF + (i * NW + w) * 512]);
    }
  };
  // LDS read address (u16 units) for row r, mfma k-step ks
  auto rdAddr = [&](int r, int ks) -> int {
    if constexpr (BK == 64) {
      return r * 64 + (((ks * 4 + lg) ^ (r & 7)) << 3);
    } else {
      int rp = r >> 1;
      return rp * 64 + ((r & 1) << 5) + (((lg ^ (rp & 3))) << 3);
    }
  };
  auto compute = [&](int buf) {
#pragma unroll
    for (int ks = 0; ks < KS; ks++) {
      bh8 am[MR], bn[NR];
#pragma unroll
      for (int mi = 0; mi < MR; mi++)
        am[mi] = *(const bh8*)&Al[buf * ABUF + rdAddr(wrow + mi * 16 + li, ks)];
#pragma unroll
      for (int ni = 0; ni < NR; ni++)
        bn[ni] = *(const bh8*)&Bl[buf * BBUF + rdAddr(wcol + ni * 16 + li, ks)];
#pragma unroll
      for (int mi = 0; mi < MR; mi++)
#pragma unroll
        for (int ni = 0; ni < NR; ni++)
          acc[mi][ni] = __builtin_amdgcn_mfma_f32_16x16x32_bf16(am[mi], bn[ni], acc[mi][ni], 0, 0, 0);
    }
  };

  stage(0, 0);
  __syncthreads();
  const int nk = K / BK;
  int cur = 0;
  for (int t = 0; t < nk - 1; t++) {
    stage(cur ^ 1, (t + 1) * BK);
    compute(cur);
    __syncthreads();
    cur ^= 1;
  }
  compute(cur);

  float bv[NR];
#pragma unroll
  for (int ni = 0; ni < NR; ni++) bv[ni] = bias[bcol + wcol + ni * 16 + li];
#pragma unroll
  for (int mi = 0; mi < MR; mi++)
#pragma unroll
    for (int rr = 0; rr < 4; rr++) {
      int row = arow + wrow + mi * 16 + lg * 4 + rr;
#pragma unroll
      for (int ni = 0; ni < NR; ni++) {
        int col = bcol + wcol + ni * 16 + li;
        float v = acc[mi][ni][rr] + bv[ni];
        if (RELU) v = fmaxf(v, 0.f);
        if (OUTBF) ((u16*)Cout)[(size_t)row * N + col] = f2bf(v);
        else ((float*)Cout)[(size_t)row * N + col] = v;
      }
    }
}

template <int NT, int BM, int BN, int BK, int RELU, int OUTBF>
__global__ __launch_bounds__(NT) void gemm2(
    const u16* __restrict__ A, const u16* __restrict__ Wt,
    const float* __restrict__ bias, void* __restrict__ Cout, int N, int K, int ntn) {
  __shared__ u16 Al[2 * BM * BK];
  __shared__ u16 Bl[2 * BN * BK];
  const int cpx = gridDim.x >> 3;
  const int swz = (blockIdx.x & 7) * cpx + (blockIdx.x >> 3);
  gemm_tile_core<NT, BM, BN, BK, RELU, OUTBF>(A, Wt, bias, Cout, N, K,
                                              (swz / ntn) * BM, (swz % ntn) * BN, Al, Bl);
}

// fused QK + V projections (independent GEMMs selected by blockIdx.y), 128x128 BK=64
__global__ __launch_bounds__(256) void gemm2_dual(
    const u16* __restrict__ A0, const u16* __restrict__ W0,
    const float* __restrict__ b0, u16* __restrict__ C0,
    const u16* __restrict__ A1, const u16* __restrict__ W1,
    const float* __restrict__ b1, u16* __restrict__ C1, int N, int K, int ntn) {
  __shared__ u16 Al[2 * 128 * 64];
  __shared__ u16 Bl[2 * 128 * 64];
  const u16* A = blockIdx.y ? A1 : A0;
  const u16* Wt = blockIdx.y ? W1 : W0;
  const float* bias = blockIdx.y ? b1 : b0;
  u16* C = blockIdx.y ? C1 : C0;
  const int cpx = gridDim.x >> 3;
  const int swz = (blockIdx.x & 7) * cpx + (blockIdx.x >> 3);
  gemm_tile_core<256, 128, 128, 64, 0, 1>(A, Wt, bias, C, N, K,
                                          (swz / ntn) * 128, (swz % ntn) * 128, Al, Bl);
}

// ---------------- flash attention: scores = (qk qk^T)*scale*fr, strict causal ----------------
// 256 q-rows per block as TWO strips (r and r+256) sharing one K/V staging.
__global__ __launch_bounds__(512) void attn_mfma(
    const u16* __restrict__ qk, const u16* __restrict__ vv,
    const float* __restrict__ fr, u16* __restrict__ att) {
  __shared__ u16 Kl[64 * 64];
  __shared__ u16 Vt[64 * 72];
  __shared__ u16 Pl[8][16 * 72];
  const int tid = threadIdx.x;
  const int lane = tid & 63, w = tid >> 6;
  const int li = lane & 15, lg = lane >> 4;
  const int bh = blockIdx.x & 127;
  const int q0 = (blockIdx.x >> 7) * 128;   // 0 or 128
  const int b = bh >> 3, h = bh & 7;

  const size_t rowbase = (size_t)(b * S) * D + h * DK;

  bh8 aq[2][2];
  float frs[2][4];
  fx4 o_[2][4];
  float m_[2][4], l_[2][4];
  const fx4 zero = {0.f, 0.f, 0.f, 0.f};
#pragma unroll
  for (int s = 0; s < 2; s++) {
    const int rs0 = q0 + s * 256 + w * 16;
#pragma unroll
    for (int ks = 0; ks < 2; ks++)
      aq[s][ks] = *(const bh8*)&qk[rowbase + (size_t)(rs0 + li) * D + ks * 32 + lg * 8];
#pragma unroll
    for (int rr = 0; rr < 4; rr++)
      frs[s][rr] = 0.125f * fr[b * S + rs0 + lg * 4 + rr];
#pragma unroll
    for (int i = 0; i < 4; i++) { o_[s][i] = zero; m_[s][i] = -1e30f; l_[s][i] = 0.f; }
  }

  const int ktmax = (q0 + 383) >> 6;   // q0=0 -> 5, q0=128 -> 7
  const int vj = tid & 63, vd0 = (tid >> 6) * 8;

  for (int kt = 0; kt <= ktmax; kt++) {
    {
      int r = tid >> 3, g = tid & 7;
      fx4 kvv = *(const fx4*)&qk[rowbase + (size_t)(kt * 64 + r) * D + ((g ^ (r & 7)) * 8)];
      *(fx4*)&Kl[r * 64 + g * 8] = kvv;
    }
    {
      u16 tmp[8];
      *(fx4*)&tmp[0] = *(const fx4*)&vv[rowbase + (size_t)(kt * 64 + vj) * D + vd0];
#pragma unroll
      for (int qd = 0; qd < 8; qd++) Vt[(vd0 + qd) * 72 + vj] = tmp[qd];
    }
    __syncthreads();

#pragma unroll
    for (int s = 0; s < 2; s++) {
      const int rs0 = q0 + s * 256 + w * 16;
      if (kt * 64 <= rs0 + 15) {
        fx4 sc[4];
#pragma unroll
        for (int jt = 0; jt < 4; jt++) sc[jt] = zero;
        __builtin_amdgcn_s_setprio(1);
#pragma unroll
        for (int ks = 0; ks < 2; ks++) {
          bh8 bk[4];
#pragma unroll
          for (int jt = 0; jt < 4; jt++) {
            int r = jt * 16 + li;
            bk[jt] = *(const bh8*)&Kl[r * 64 + (((ks * 4 + lg) ^ (r & 7)) * 8)];
          }
#pragma unroll
          for (int jt = 0; jt < 4; jt++)
            sc[jt] = __builtin_amdgcn_mfma_f32_16x16x32_bf16(aq[s][ks], bk[jt], sc[jt], 0, 0, 0);
        }
        __builtin_amdgcn_s_setprio(0);

        const bool diag = (kt == (rs0 >> 6));
        const int rbase = rs0 & 63;
#pragma unroll
        for (int jt = 0; jt < 4; jt++)
#pragma unroll
          for (int rr = 0; rr < 4; rr++) {
            float sv = sc[jt][rr] * frs[s][rr];
            if (diag && (jt * 16 + li >= rbase + lg * 4 + rr)) sv = -1e30f;
            sc[jt][rr] = sv;
          }

#pragma unroll
        for (int rr = 0; rr < 4; rr++) {
          float v0 = fmaxf(fmaxf(sc[0][rr], sc[1][rr]), fmaxf(sc[2][rr], sc[3][rr]));
          v0 = fmaxf(v0, __shfl_xor(v0, 1));
          v0 = fmaxf(v0, __shfl_xor(v0, 2));
          v0 = fmaxf(v0, __shfl_xor(v0, 4));
          v0 = fmaxf(v0, __shfl_xor(v0, 8));
          float mn = fmaxf(m_[s][rr], v0);
          float cf = __expf(m_[s][rr] - mn);
          m_[s][rr] = mn;
          float ps = 0.f;
#pragma unroll
          for (int jt = 0; jt < 4; jt++) {
            float e = __expf(sc[jt][rr] - mn);
            sc[jt][rr] = e;
            ps += e;
          }
          ps += __shfl_xor(ps, 1);
          ps += __shfl_xor(ps, 2);
          ps += __shfl_xor(ps, 4);
          ps += __shfl_xor(ps, 8);
          l_[s][rr] = l_[s][rr] * cf + ps;
#pragma unroll
          for (int dt = 0; dt < 4; dt++) o_[s][dt][rr] *= cf;
        }

#pragma unroll
        for (int jt = 0; jt < 4; jt++)
#pragma unroll
          for (int rr = 0; rr < 4; rr++)
            Pl[w][(lg * 4 + rr) * 72 + jt * 16 + li] = f2bf(sc[jt][rr]);

        __builtin_amdgcn_s_setprio(1);
#pragma unroll
        for (int ks = 0; ks < 2; ks++) {
          bh8 pa = *(const bh8*)&Pl[w][li * 72 + ks * 32 + lg * 8];
          bh8 bvf[4];
#pragma unroll
          for (int dt = 0; dt < 4; dt++)
            bvf[dt] = *(const bh8*)&Vt[(dt * 16 + li) * 72 + ks * 32 + lg * 8];
#pragma unroll
          for (int dt = 0; dt < 4; dt++)
            o_[s][dt] = __builtin_amdgcn_mfma_f32_16x16x32_bf16(pa, bvf[dt], o_[s][dt], 0, 0, 0);
        }
        __builtin_amdgcn_s_setprio(0);
      }
    }
    __syncthreads();
  }

#pragma unroll
  for (int s = 0; s < 2; s++) {
#pragma unroll
    for (int rr = 0; rr < 4; rr++) {
      int rs = q0 + s * 256 + w * 16 + lg * 4 + rr;
      float inv = (rs == 0) ? 0.f : 1.f / l_[s][rr];
#pragma unroll
      for (int dt = 0; dt < 4; dt++)
        att[rowbase + (size_t)rs * D + dt * 16 + li] = f2bf(o_[s][dt][rr] * inv);
    }
  }
}

// ---------------- residual + LayerNorm: bf16 residual in, bf16 (and optional f32) out ----------------
__global__ __launch_bounds__(256) void add_ln(
    const u16* __restrict__ xinb, const u16* __restrict__ pb,
    const float* __restrict__ g, const float* __restrict__ bta,
    float* __restrict__ xoutf, u16* __restrict__ xb) {
  const int w = threadIdx.x >> 6, lane = threadIdx.x & 63;
  const int row = blockIdx.x * 4 + w;
  const u16* xi = &xinb[(size_t)row * D];
  const u16* pp = &pb[(size_t)row * D];

  sh4 x0 = *(const sh4*)&xi[lane * 4];
  sh4 x1 = *(const sh4*)&xi[256 + lane * 4];
  sh4 p0 = *(const sh4*)&pp[lane * 4];
  sh4 p1 = *(const sh4*)&pp[256 + lane * 4];
  float v[8] = {bf2f((u16)x0.x) + bf2f((u16)p0.x), bf2f((u16)x0.y) + bf2f((u16)p0.y),
                bf2f((u16)x0.z) + bf2f((u16)p0.z), bf2f((u16)x0.w) + bf2f((u16)p0.w),
                bf2f((u16)x1.x) + bf2f((u16)p1.x), bf2f((u16)x1.y) + bf2f((u16)p1.y),
                bf2f((u16)x1.z) + bf2f((u16)p1.z), bf2f((u16)x1.w) + bf2f((u16)p1.w)};

  float s = 0.f;
#pragma unroll
  for (int i = 0; i < 8; i++) s += v[i];
#pragma unroll
  for (int d = 1; d < 64; d <<= 1) s += __shfl_xor(s, d);
  const float mu = s * (1.0f / D);

  float vs = 0.f;
#pragma unroll
  for (int i = 0; i < 8; i++) { v[i] -= mu; vs += v[i] * v[i]; }
#pragma unroll
  for (int d = 1; d < 64; d <<= 1) vs += __shfl_xor(vs, d);
  const float rs = rsqrtf(vs * (1.0f / D) + 1e-5f);

  float4 g0 = *(const float4*)&g[lane * 4];
  float4 b0 = *(const float4*)&bta[lane * 4];
  float4 g1 = *(const float4*)&g[256 + lane * 4];
  float4 b1 = *(const float4*)&bta[256 + lane * 4];
  float o[8];
  o[0] = v[0] * rs * g0.x + b0.x; o[1] = v[1] * rs * g0.y + b0.y;
  o[2] = v[2] * rs * g0.z + b0.z; o[3] = v[3] * rs * g0.w + b0.w;
  o[4] = v[4] * rs * g1.x + b1.x; o[5] = v[5] * rs * g1.y + b1.y;
  o[6] = v[6] * rs * g1.z + b1.z; o[7] = v[7] * rs * g1.w + b1.w;

  if (xoutf) {
    *(float4*)&xoutf[(size_t)row * D + lane * 4] = *(float4*)&o[0];
    *(float4*)&xoutf[(size_t)row * D + 256 + lane * 4] = *(float4*)&o[4];
  }
  if (xb) {
    u16 ob[8];
#pragma unroll
    for (int i = 0; i < 8; i++) ob[i] = f2bf(o[i]);
    *(sh4*)&xb[(size_t)row * D + lane * 4] = *(sh4*)&ob[0];
    *(sh4*)&xb[(size_t)row * D + 256 + lane * 4] = *(sh4*)&ob[4];
  }
}

extern "C" void kernel_launch(void* const* d_in, const int* in_sizes, int n_in,
                              void* d_out, int out_size, void* d_ws, size_t ws_size,
                              hipStream_t stream) {
  const float* q_embed = (const float*)d_in[0];
  const float* qa_embed = (const float*)d_in[1];
  const float* forget_rate = (const float*)d_in[2];
  const float* pe = (const float*)d_in[3];
  const float* Wk = (const float*)d_in[4];
  const float* bk = (const float*)d_in[5];
  const float* Wv = (const float*)d_in[6];
  const float* bv = (const float*)d_in[7];
  const float* Wo = (const float*)d_in[8];
  const float* bo = (const float*)d_in[9];
  const float* ln1_g = (const float*)d_in[10];
  const float* ln1_b = (const float*)d_in[11];
  const float* W1 = (const float*)d_in[12];
  const float* b1 = (const float*)d_in[13];
  const float* W2 = (const float*)d_in[14];
  const float* b2 = (const float*)d_in[15];
  const float* ln2_g = (const float*)d_in[16];
  const float* ln2_b = (const float*)d_in[17];

  const size_t nMD = (size_t)M * D;
  char* p = (char*)d_ws;
  u16* projb = (u16*)p;      p += nMD * 2;
  u16* xb = (u16*)p;         p += nMD * 2;
  u16* yb = (u16*)p;         p += nMD * 2;
  u16* qkb = (u16*)p;        p += nMD * 2;
  u16* vvb = (u16*)p;        p += nMD * 2;
  u16* attb = (u16*)p;       p += nMD * 2;
  u16* hb = (u16*)p;         p += (size_t)M * DFF * 2;
  u16* Wkt = (u16*)p;        p += (size_t)NL * D * D * 2;
  u16* Wvt = (u16*)p;        p += (size_t)NL * D * D * 2;
  u16* Wot = (u16*)p;        p += (size_t)NL * D * D * 2;
  u16* W1t = (u16*)p;        p += (size_t)NL * D * DFF * 2;
  u16* W2t = (u16*)p;        p += (size_t)NL * DFF * D * 2;

  add_pe<<<(B * S * D) / 256, 256, 0, stream>>>(q_embed, qa_embed, pe, xb, yb);
  transpose_cvt3<<<dim3(D / 64, D / 64, 3 * NL), 256, 0, stream>>>(Wk, Wv, Wo, Wkt, Wvt, Wot);
  transpose_cvt<<<dim3(DFF / 64, D / 64, NL), 256, 0, stream>>>(W1, W1t, D, DFF);
  transpose_cvt<<<dim3(D / 64, DFF / 64, NL), 256, 0, stream>>>(W2, W2t, DFF, D);

  const int gD = (M / 64) * (D / 128);       // 512
  const int gD128 = (M / 128) * (D / 128);   // 256 (x2 via blockIdx.y in dual)
  const int gF128 = (M / 128) * (DFF / 128); // 1024

  for (int l = 0; l < NL; l++) {
    gemm2_dual<<<dim3(gD128, 2), 256, 0, stream>>>(
        xb, Wkt + (size_t)l * D * D, bk + l * D, qkb,
        yb, Wvt + (size_t)l * D * D, bv + l * D, vvb, D, D, D / 128);
    attn_mfma<<<256, 512, 0, stream>>>(qkb, vvb, forget_rate, attb);
    gemm2<256, 64, 128, 32, 0, 1><<<gD, 256, 0, stream>>>(
        attb, Wot + (size_t)l * D * D, bo + l * D, projb, D, D, D / 128);
    add_ln<<<M / 4, 256, 0, stream>>>(xb, projb, ln1_g + l * D, ln1_b + l * D,
                                      (float*)nullptr, xb);
    gemm2<256, 128, 128, 32, 1, 1><<<gF128, 256, 0, stream>>>(
        xb, W1t + (size_t)l * D * DFF, b1 + l * DFF, hb, DFF, D, DFF / 128);
    gemm2<256, 64, 128, 32, 0, 1><<<gD, 256, 0, stream>>>(
        hb, W2t + (size_t)l * DFF * D, b2 + l * D, projb, D, DFF, D / 128);
    float* xo = (l == NL - 1) ? (float*)d_out : (float*)nullptr;
    u16* xbo = (l == NL - 1) ? (u16*)nullptr : xb;
    add_ln<<<M / 4, 256, 0, stream>>>(xb, projb, ln2_g + l * D, ln2_b + l * D, xo, xbo);
  }
}

// Round 18
// 529.701 us; speedup vs baseline: 1.0441x; 1.0225x over previous
//
#include <hip/hip_runtime.h>

typedef unsigned short u16;
typedef __attribute__((ext_vector_type(8))) short bh8;   // 8 bf16 in 4 VGPRs
typedef __attribute__((ext_vector_type(4))) short sh4;   // 4 bf16 = 8B
typedef __attribute__((ext_vector_type(4))) float fx4;

constexpr int B = 16, S = 512, D = 512, H = 8, DFF = 2048, NL = 4, DK = 64;
constexpr int M = B * S;  // 8192

__device__ __forceinline__ u16 f2bf(float f) {
  union { float f; unsigned u; } v; v.f = f;
  unsigned r = v.u + 0x7fffu + ((v.u >> 16) & 1u);
  return (u16)(r >> 16);
}
__device__ __forceinline__ float bf2f(u16 b) {
  union { unsigned u; float f; } v; v.u = ((unsigned)b) << 16;
  return v.f;
}

__device__ __forceinline__ void gload16(const void* g, void* l) {
  __builtin_amdgcn_global_load_lds((const __attribute__((address_space(1))) void*)g,
                                   (__attribute__((address_space(3))) void*)l,
                                   16, 0, 0);
}

// ---------------- xb = bf16(q + pe), yb = bf16(qa + pe) ----------------
__global__ __launch_bounds__(256) void add_pe(
    const float* __restrict__ q, const float* __restrict__ qa,
    const float* __restrict__ pe,
    u16* __restrict__ xb, u16* __restrict__ yb) {
  int idx = blockIdx.x * 256 + threadIdx.x;
  float pv = pe[idx & (S * D - 1)];
  xb[idx] = f2bf(q[idx] + pv);
  yb[idx] = f2bf(qa[idx] + pv);
}

// ---------------- weight transpose+convert: src f32 [K][N] -> dst bf16 [N][K] ----------------
__device__ __forceinline__ void transpose_tile(
    const float* __restrict__ s, u16* __restrict__ d, int K, int N,
    int k0, int n0) {
  __shared__ float t[64][65];
  const int tid = threadIdx.x;
  const int r = tid >> 2, c0 = (tid & 3) * 16;
#pragma unroll
  for (int i = 0; i < 16; i += 4) {
    float4 v = *(const float4*)&s[(size_t)(k0 + r) * N + n0 + c0 + i];
    t[r][c0 + i] = v.x; t[r][c0 + i + 1] = v.y;
    t[r][c0 + i + 2] = v.z; t[r][c0 + i + 3] = v.w;
  }
  __syncthreads();
  u16 tmp[16];
#pragma unroll
  for (int i = 0; i < 16; i++) tmp[i] = f2bf(t[c0 + i][r]);
  *(fx4*)&d[(size_t)(n0 + r) * K + k0 + c0] = *(fx4*)&tmp[0];
  *(fx4*)&d[(size_t)(n0 + r) * K + k0 + c0 + 8] = *(fx4*)&tmp[8];
}

__global__ __launch_bounds__(256) void transpose_cvt(
    const float* __restrict__ src, u16* __restrict__ dst, int K, int N) {
  const int l = blockIdx.z;
  transpose_tile(src + (size_t)l * K * N, dst + (size_t)l * N * K, K, N,
                 blockIdx.y * 64, blockIdx.x * 64);
}

__global__ __launch_bounds__(256) void transpose_cvt3(
    const float* __restrict__ Wk, const float* __restrict__ Wv,
    const float* __restrict__ Wo, u16* __restrict__ Wkt,
    u16* __restrict__ Wvt, u16* __restrict__ Wot) {
  const int z = blockIdx.z;
  const int which = z >> 2, l = z & 3;
  const float* s = (which == 0 ? Wk : which == 1 ? Wv : Wo) + (size_t)l * D * D;
  u16* d = (which == 0 ? Wkt : which == 1 ? Wvt : Wot) + (size_t)l * D * D;
  transpose_tile(s, d, D, D, blockIdx.y * 64, blockIdx.x * 64);
}

// ---------------- bf16 MFMA GEMM tile core: 2-phase double-buffered, BK=64 ----------------
template <int NT, int BM, int BN, int RELU, int OUTBF>
__device__ __forceinline__ void gemm_tile_core(
    const u16* __restrict__ A, const u16* __restrict__ Wt,
    const float* __restrict__ bias, void* __restrict__ Cout,
    int N, int K, int arow, int bcol, u16* Al, u16* Bl) {
  constexpr int NW = NT / 64;
  constexpr int WC = NW / 2;
  constexpr int MR = BM / 32;
  constexpr int NR = BN / (WC * 16);
  constexpr int ACH = (BM * 8) / NT, BCH = (BN * 8) / NT;
  constexpr int ABUF = BM * 64, BBUF = BN * 64;

  const int tid = threadIdx.x;
  const int lane = tid & 63, w = tid >> 6;
  const int li = lane & 15, lg = lane >> 4;
  const int wrow = (w / WC) * (BM / 2), wcol = (w % WC) * (BN / WC);

  const fx4 zero = {0.f, 0.f, 0.f, 0.f};
  fx4 acc[MR][NR];
#pragma unroll
  for (int i = 0; i < MR; i++)
#pragma unroll
    for (int j = 0; j < NR; j++) acc[i][j] = zero;

  auto stage = [&](int buf, int k0) {
#pragma unroll
    for (int i = 0; i < ACH; i++) {
      int c = i * NT + tid, r = c >> 3, g = c & 7;
      gload16(&A[(size_t)(arow + r) * K + k0 + ((g ^ (r & 7)) << 3)],
              &Al[buf * ABUF + (i * NW + w) * 512]);
    }
#pragma unroll
    for (int i = 0; i < BCH; i++) {
      int c = i * NT + tid, r = c >> 3, g = c & 7;
      gload16(&Wt[(size_t)(bcol + r) * K + k0 + ((g ^ (r & 7)) << 3)],
              &Bl[buf * BBUF + (i * NW + w) * 512]);
    }
  };
  auto compute = [&](int buf) {
#pragma unroll
    for (int ks = 0; ks < 2; ks++) {
      bh8 am[MR], bn[NR];
#pragma unroll
      for (int mi = 0; mi < MR; mi++) {
        int r = wrow + mi * 16 + li;
        am[mi] = *(const bh8*)&Al[buf * ABUF + r * 64 + (((ks * 4 + lg) ^ (r & 7)) << 3)];
      }
#pragma unroll
      for (int ni = 0; ni < NR; ni++) {
        int r = wcol + ni * 16 + li;
        bn[ni] = *(const bh8*)&Bl[buf * BBUF + r * 64 + (((ks * 4 + lg) ^ (r & 7)) << 3)];
      }
#pragma unroll
      for (int mi = 0; mi < MR; mi++)
#pragma unroll
        for (int ni = 0; ni < NR; ni++)
          acc[mi][ni] = __builtin_amdgcn_mfma_f32_16x16x32_bf16(am[mi], bn[ni], acc[mi][ni], 0, 0, 0);
    }
  };

  stage(0, 0);
  __syncthreads();
  const int nk = K >> 6;
  int cur = 0;
  for (int t = 0; t < nk - 1; t++) {
    stage(cur ^ 1, (t + 1) << 6);
    compute(cur);
    __syncthreads();
    cur ^= 1;
  }
  compute(cur);

  float bv[NR];
#pragma unroll
  for (int ni = 0; ni < NR; ni++) bv[ni] = bias[bcol + wcol + ni * 16 + li];
#pragma unroll
  for (int mi = 0; mi < MR; mi++)
#pragma unroll
    for (int rr = 0; rr < 4; rr++) {
      int row = arow + wrow + mi * 16 + lg * 4 + rr;
#pragma unroll
      for (int ni = 0; ni < NR; ni++) {
        int col = bcol + wcol + ni * 16 + li;
        float v = acc[mi][ni][rr] + bv[ni];
        if (RELU) v = fmaxf(v, 0.f);
        if (OUTBF) ((u16*)Cout)[(size_t)row * N + col] = f2bf(v);
        else ((float*)Cout)[(size_t)row * N + col] = v;
      }
    }
}

template <int NT, int BM, int BN, int RELU, int OUTBF>
__global__ __launch_bounds__(NT) void gemm2(
    const u16* __restrict__ A, const u16* __restrict__ Wt,
    const float* __restrict__ bias, void* __restrict__ Cout, int N, int K, int ntn) {
  __shared__ u16 Al[2 * BM * 64];
  __shared__ u16 Bl[2 * BN * 64];
  const int cpx = gridDim.x >> 3;
  const int swz = (blockIdx.x & 7) * cpx + (blockIdx.x >> 3);
  gemm_tile_core<NT, BM, BN, RELU, OUTBF>(A, Wt, bias, Cout, N, K,
                                          (swz / ntn) * BM, (swz % ntn) * BN, Al, Bl);
}

// fused QK + V projections (independent GEMMs selected by blockIdx.y), 128x128 BK=64
__global__ __launch_bounds__(256) void gemm2_dual(
    const u16* __restrict__ A0, const u16* __restrict__ W0,
    const float* __restrict__ b0, u16* __restrict__ C0,
    const u16* __restrict__ A1, const u16* __restrict__ W1,
    const float* __restrict__ b1, u16* __restrict__ C1, int N, int K, int ntn) {
  __shared__ u16 Al[2 * 128 * 64];
  __shared__ u16 Bl[2 * 128 * 64];
  const u16* A = blockIdx.y ? A1 : A0;
  const u16* Wt = blockIdx.y ? W1 : W0;
  const float* bias = blockIdx.y ? b1 : b0;
  u16* C = blockIdx.y ? C1 : C0;
  const int cpx = gridDim.x >> 3;
  const int swz = (blockIdx.x & 7) * cpx + (blockIdx.x >> 3);
  gemm_tile_core<256, 128, 128, 0, 1>(A, Wt, bias, C, N, K,
                                      (swz / ntn) * 128, (swz % ntn) * 128, Al, Bl);
}

// ---------------- flash attention: scores = (qk qk^T)*scale*fr, strict causal ----------------
// 256 q-rows per block as TWO strips (r and r+256) sharing one K/V staging.
__global__ __launch_bounds__(512) void attn_mfma(
    const u16* __restrict__ qk, const u16* __restrict__ vv,
    const float* __restrict__ fr, u16* __restrict__ att) {
  __shared__ u16 Kl[64 * 64];
  __shared__ u16 Vt[64 * 72];
  __shared__ u16 Pl[8][16 * 72];
  const int tid = threadIdx.x;
  const int lane = tid & 63, w = tid >> 6;
  const int li = lane & 15, lg = lane >> 4;
  const int bh = blockIdx.x & 127;
  const int q0 = (blockIdx.x >> 7) * 128;   // 0 or 128
  const int b = bh >> 3, h = bh & 7;

  const size_t rowbase = (size_t)(b * S) * D + h * DK;

  bh8 aq[2][2];
  float frs[2][4];
  fx4 o_[2][4];
  float m_[2][4], l_[2][4];
  const fx4 zero = {0.f, 0.f, 0.f, 0.f};
#pragma unroll
  for (int s = 0; s < 2; s++) {
    const int rs0 = q0 + s * 256 + w * 16;
#pragma unroll
    for (int ks = 0; ks < 2; ks++)
      aq[s][ks] = *(const bh8*)&qk[rowbase + (size_t)(rs0 + li) * D + ks * 32 + lg * 8];
#pragma unroll
    for (int rr = 0; rr < 4; rr++)
      frs[s][rr] = 0.125f * fr[b * S + rs0 + lg * 4 + rr];
#pragma unroll
    for (int i = 0; i < 4; i++) { o_[s][i] = zero; m_[s][i] = -1e30f; l_[s][i] = 0.f; }
  }

  const int ktmax = (q0 + 383) >> 6;   // q0=0 -> 5, q0=128 -> 7
  const int vj = tid & 63, vd0 = (tid >> 6) * 8;

  for (int kt = 0; kt <= ktmax; kt++) {
    {
      int r = tid >> 3, g = tid & 7;
      fx4 kvv = *(const fx4*)&qk[rowbase + (size_t)(kt * 64 + r) * D + ((g ^ (r & 7)) * 8)];
      *(fx4*)&Kl[r * 64 + g * 8] = kvv;
    }
    {
      u16 tmp[8];
      *(fx4*)&tmp[0] = *(const fx4*)&vv[rowbase + (size_t)(kt * 64 + vj) * D + vd0];
#pragma unroll
      for (int qd = 0; qd < 8; qd++) Vt[(vd0 + qd) * 72 + vj] = tmp[qd];
    }
    __syncthreads();

#pragma unroll
    for (int s = 0; s < 2; s++) {
      const int rs0 = q0 + s * 256 + w * 16;
      if (kt * 64 <= rs0 + 15) {
        fx4 sc[4];
#pragma unroll
        for (int jt = 0; jt < 4; jt++) sc[jt] = zero;
        __builtin_amdgcn_s_setprio(1);
#pragma unroll
        for (int ks = 0; ks < 2; ks++) {
          bh8 bk[4];
#pragma unroll
          for (int jt = 0; jt < 4; jt++) {
            int r = jt * 16 + li;
            bk[jt] = *(const bh8*)&Kl[r * 64 + (((ks * 4 + lg) ^ (r & 7)) * 8)];
          }
#pragma unroll
          for (int jt = 0; jt < 4; jt++)
            sc[jt] = __builtin_amdgcn_mfma_f32_16x16x32_bf16(aq[s][ks], bk[jt], sc[jt], 0, 0, 0);
        }
        __builtin_amdgcn_s_setprio(0);

        const bool diag = (kt == (rs0 >> 6));
        const int rbase = rs0 & 63;
#pragma unroll
        for (int jt = 0; jt < 4; jt++)
#pragma unroll
          for (int rr = 0; rr < 4; rr++) {
            float sv = sc[jt][rr] * frs[s][rr];
            if (diag && (jt * 16 + li >= rbase + lg * 4 + rr)) sv = -1e30f;
            sc[jt][rr] = sv;
          }

#pragma unroll
        for (int rr = 0; rr < 4; rr++) {
          float v0 = fmaxf(fmaxf(sc[0][rr], sc[1][rr]), fmaxf(sc[2][rr], sc[3][rr]));
          v0 = fmaxf(v0, __shfl_xor(v0, 1));
          v0 = fmaxf(v0, __shfl_xor(v0, 2));
          v0 = fmaxf(v0, __shfl_xor(v0, 4));
          v0 = fmaxf(v0, __shfl_xor(v0, 8));
          float mn = fmaxf(m_[s][rr], v0);
          float cf = __expf(m_[s][rr] - mn);
          m_[s][rr] = mn;
          float ps = 0.f;
#pragma unroll
          for (int jt = 0; jt < 4; jt++) {
            float e = __expf(sc[jt][rr] - mn);
            sc[jt][rr] = e;
            ps += e;
          }
          ps += __shfl_xor(ps, 1);
          ps += __shfl_xor(ps, 2);
          ps += __shfl_xor(ps, 4);
          ps += __shfl_xor(ps, 8);
          l_[s][rr] = l_[s][rr] * cf + ps;
#pragma unroll
          for (int dt = 0; dt < 4; dt++) o_[s][dt][rr] *= cf;
        }

#pragma unroll
        for (int jt = 0; jt < 4; jt++)
#pragma unroll
          for (int rr = 0; rr < 4; rr++)
            Pl[w][(lg * 4 + rr) * 72 + jt * 16 + li] = f2bf(sc[jt][rr]);

        __builtin_amdgcn_s_setprio(1);
#pragma unroll
        for (int ks = 0; ks < 2; ks++) {
          bh8 pa = *(const bh8*)&Pl[w][li * 72 + ks * 32 + lg * 8];
          bh8 bvf[4];
#pragma unroll
          for (int dt = 0; dt < 4; dt++)
            bvf[dt] = *(const bh8*)&Vt[(dt * 16 + li) * 72 + ks * 32 + lg * 8];
#pragma unroll
          for (int dt = 0; dt < 4; dt++)
            o_[s][dt] = __builtin_amdgcn_mfma_f32_16x16x32_bf16(pa, bvf[dt], o_[s][dt], 0, 0, 0);
        }
        __builtin_amdgcn_s_setprio(0);
      }
    }
    __syncthreads();
  }

#pragma unroll
  for (int s = 0; s < 2; s++) {
#pragma unroll
    for (int rr = 0; rr < 4; rr++) {
      int rs = q0 + s * 256 + w * 16 + lg * 4 + rr;
      float inv = (rs == 0) ? 0.f : 1.f / l_[s][rr];
#pragma unroll
      for (int dt = 0; dt < 4; dt++)
        att[rowbase + (size_t)rs * D + dt * 16 + li] = f2bf(o_[s][dt][rr] * inv);
    }
  }
}

// ---------------- residual + LayerNorm: bf16 residual in, bf16 (and optional f32) out ----------------
__global__ __launch_bounds__(256) void add_ln(
    const u16* __restrict__ xinb, const u16* __restrict__ pb,
    const float* __restrict__ g, const float* __restrict__ bta,
    float* __restrict__ xoutf, u16* __restrict__ xb) {
  const int w = threadIdx.x >> 6, lane = threadIdx.x & 63;
  const int row = blockIdx.x * 4 + w;
  const u16* xi = &xinb[(size_t)row * D];
  const u16* pp = &pb[(size_t)row * D];

  sh4 x0 = *(const sh4*)&xi[lane * 4];
  sh4 x1 = *(const sh4*)&xi[256 + lane * 4];
  sh4 p0 = *(const sh4*)&pp[lane * 4];
  sh4 p1 = *(const sh4*)&pp[256 + lane * 4];
  float v[8] = {bf2f((u16)x0.x) + bf2f((u16)p0.x), bf2f((u16)x0.y) + bf2f((u16)p0.y),
                bf2f((u16)x0.z) + bf2f((u16)p0.z), bf2f((u16)x0.w) + bf2f((u16)p0.w),
                bf2f((u16)x1.x) + bf2f((u16)p1.x), bf2f((u16)x1.y) + bf2f((u16)p1.y),
                bf2f((u16)x1.z) + bf2f((u16)p1.z), bf2f((u16)x1.w) + bf2f((u16)p1.w)};

  float s = 0.f;
#pragma unroll
  for (int i = 0; i < 8; i++) s += v[i];
#pragma unroll
  for (int d = 1; d < 64; d <<= 1) s += __shfl_xor(s, d);
  const float mu = s * (1.0f / D);

  float vs = 0.f;
#pragma unroll
  for (int i = 0; i < 8; i++) { v[i] -= mu; vs += v[i] * v[i]; }
#pragma unroll
  for (int d = 1; d < 64; d <<= 1) vs += __shfl_xor(vs, d);
  const float rs = rsqrtf(vs * (1.0f / D) + 1e-5f);

  float4 g0 = *(const float4*)&g[lane * 4];
  float4 b0 = *(const float4*)&bta[lane * 4];
  float4 g1 = *(const float4*)&g[256 + lane * 4];
  float4 b1 = *(const float4*)&bta[256 + lane * 4];
  float o[8];
  o[0] = v[0] * rs * g0.x + b0.x; o[1] = v[1] * rs * g0.y + b0.y;
  o[2] = v[2] * rs * g0.z + b0.z; o[3] = v[3] * rs * g0.w + b0.w;
  o[4] = v[4] * rs * g1.x + b1.x; o[5] = v[5] * rs * g1.y + b1.y;
  o[6] = v[6] * rs * g1.z + b1.z; o[7] = v[7] * rs * g1.w + b1.w;

  if (xoutf) {
    *(float4*)&xoutf[(size_t)row * D + lane * 4] = *(float4*)&o[0];
    *(float4*)&xoutf[(size_t)row * D + 256 + lane * 4] = *(float4*)&o[4];
  }
  if (xb) {
    u16 ob[8];
#pragma unroll
    for (int i = 0; i < 8; i++) ob[i] = f2bf(o[i]);
    *(sh4*)&xb[(size_t)row * D + lane * 4] = *(sh4*)&ob[0];
    *(sh4*)&xb[(size_t)row * D + 256 + lane * 4] = *(sh4*)&ob[4];
  }
}

extern "C" void kernel_launch(void* const* d_in, const int* in_sizes, int n_in,
                              void* d_out, int out_size, void* d_ws, size_t ws_size,
                              hipStream_t stream) {
  const float* q_embed = (const float*)d_in[0];
  const float* qa_embed = (const float*)d_in[1];
  const float* forget_rate = (const float*)d_in[2];
  const float* pe = (const float*)d_in[3];
  const float* Wk = (const float*)d_in[4];
  const float* bk = (const float*)d_in[5];
  const float* Wv = (const float*)d_in[6];
  const float* bv = (const float*)d_in[7];
  const float* Wo = (const float*)d_in[8];
  const float* bo = (const float*)d_in[9];
  const float* ln1_g = (const float*)d_in[10];
  const float* ln1_b = (const float*)d_in[11];
  const float* W1 = (const float*)d_in[12];
  const float* b1 = (const float*)d_in[13];
  const float* W2 = (const float*)d_in[14];
  const float* b2 = (const float*)d_in[15];
  const float* ln2_g = (const float*)d_in[16];
  const float* ln2_b = (const float*)d_in[17];

  const size_t nMD = (size_t)M * D;
  char* p = (char*)d_ws;
  u16* projb = (u16*)p;      p += nMD * 2;
  u16* xb = (u16*)p;         p += nMD * 2;
  u16* yb = (u16*)p;         p += nMD * 2;
  u16* qkb = (u16*)p;        p += nMD * 2;
  u16* vvb = (u16*)p;        p += nMD * 2;
  u16* attb = (u16*)p;       p += nMD * 2;
  u16* hb = (u16*)p;         p += (size_t)M * DFF * 2;
  u16* Wkt = (u16*)p;        p += (size_t)NL * D * D * 2;
  u16* Wvt = (u16*)p;        p += (size_t)NL * D * D * 2;
  u16* Wot = (u16*)p;        p += (size_t)NL * D * D * 2;
  u16* W1t = (u16*)p;        p += (size_t)NL * D * DFF * 2;
  u16* W2t = (u16*)p;        p += (size_t)NL * DFF * D * 2;

  add_pe<<<(B * S * D) / 256, 256, 0, stream>>>(q_embed, qa_embed, pe, xb, yb);
  transpose_cvt3<<<dim3(D / 64, D / 64, 3 * NL), 256, 0, stream>>>(Wk, Wv, Wo, Wkt, Wvt, Wot);
  transpose_cvt<<<dim3(DFF / 64, D / 64, NL), 256, 0, stream>>>(W1, W1t, D, DFF);
  transpose_cvt<<<dim3(D / 64, DFF / 64, NL), 256, 0, stream>>>(W2, W2t, DFF, D);

  const int gD = (M / 64) * (D / 128);       // 512
  const int gD128 = (M / 128) * (D / 128);   // 256 (x2 via blockIdx.y in dual)
  const int gF = (M / 128) * (DFF / 256);    // 512

  for (int l = 0; l < NL; l++) {
    gemm2_dual<<<dim3(gD128, 2), 256, 0, stream>>>(
        xb, Wkt + (size_t)l * D * D, bk + l * D, qkb,
        yb, Wvt + (size_t)l * D * D, bv + l * D, vvb, D, D, D / 128);
    attn_mfma<<<256, 512, 0, stream>>>(qkb, vvb, forget_rate, attb);
    gemm2<256, 64, 128, 0, 1><<<gD, 256, 0, stream>>>(
        attb, Wot + (size_t)l * D * D, bo + l * D, projb, D, D, D / 128);
    add_ln<<<M / 4, 256, 0, stream>>>(xb, projb, ln1_g + l * D, ln1_b + l * D,
                                      (float*)nullptr, xb);
    gemm2<512, 128, 256, 1, 1><<<gF, 512, 0, stream>>>(
        xb, W1t + (size_t)l * D * DFF, b1 + l * DFF, hb, DFF, D, DFF / 256);
    gemm2<256, 64, 128, 0, 1><<<gD, 256, 0, stream>>>(
        hb, W2t + (size_t)l * DFF * D, b2 + l * D, projb, D, DFF, D / 128);
    float* xo = (l == NL - 1) ? (float*)d_out : (float*)nullptr;
    u16* xbo = (l == NL - 1) ? (u16*)nullptr : xb;
    add_ln<<<M / 4, 256, 0, stream>>>(xb, projb, ln2_g + l * D, ln2_b + l * D, xo, xbo);
  }
}